// Round 2
// baseline (596.525 us; speedup 1.0000x reference)
//
#include <hip/hip_runtime.h>
#include <math.h>

#define NODES 100000
#define NEDGE 1600000
#define ETOT  (NEDGE + NODES)
#define FIN   128
#define C1    64
#define NEG   0.2f
#define BNEPS 1e-5f
#define BNBLK 256

// ---------------- CSR build ----------------

__global__ __launch_bounds__(256) void k_init_counts(int* counts) {
    int n = blockIdx.x * 256 + threadIdx.x;
    if (n < NODES) counts[n] = 1;   // self-loop
}

__global__ __launch_bounds__(256) void k_count_edges(const int* __restrict__ ei, int* counts) {
    int e = blockIdx.x * 256 + threadIdx.x;
    if (e < NEDGE) {
        unsigned d = (unsigned)ei[NEDGE + e];
        if (d < NODES) atomicAdd(&counts[d], 1);
    }
}

// exclusive scan, 1024 items/block (256 thr x 4)
__global__ __launch_bounds__(256) void k_scan1(const int* __restrict__ in, int* __restrict__ out,
                                               int* __restrict__ bsums, int n) {
    __shared__ int lds[256];
    int t = threadIdx.x;
    int base = blockIdx.x * 1024 + t * 4;
    int v0 = (base + 0) < n ? in[base + 0] : 0;
    int v1 = (base + 1) < n ? in[base + 1] : 0;
    int v2 = (base + 2) < n ? in[base + 2] : 0;
    int v3 = (base + 3) < n ? in[base + 3] : 0;
    int tot = v0 + v1 + v2 + v3;
    lds[t] = tot;
    __syncthreads();
    for (int o = 1; o < 256; o <<= 1) {
        int add = (t >= o) ? lds[t - o] : 0;
        __syncthreads();
        lds[t] += add;
        __syncthreads();
    }
    int excl = lds[t] - tot;
    if (base + 0 < n) out[base + 0] = excl;
    if (base + 1 < n) out[base + 1] = excl + v0;
    if (base + 2 < n) out[base + 2] = excl + v0 + v1;
    if (base + 3 < n) out[base + 3] = excl + v0 + v1 + v2;
    if (t == 255) bsums[blockIdx.x] = lds[255];
}

__global__ __launch_bounds__(128) void k_scan2(int* bsums, int nb) {
    __shared__ int lds[128];
    int t = threadIdx.x;
    int own = (t < nb) ? bsums[t] : 0;
    lds[t] = own;
    __syncthreads();
    for (int o = 1; o < 128; o <<= 1) {
        int add = (t >= o) ? lds[t - o] : 0;
        __syncthreads();
        lds[t] += add;
        __syncthreads();
    }
    if (t < nb) bsums[t] = lds[t] - own;  // exclusive
}

__global__ __launch_bounds__(256) void k_scan3(int* __restrict__ out, const int* __restrict__ bsums,
                                               int* __restrict__ cursor, int n) {
    int t = threadIdx.x;
    int base = blockIdx.x * 1024 + t * 4;
    int boff = bsums[blockIdx.x];
    #pragma unroll
    for (int i = 0; i < 4; i++) {
        int idx = base + i;
        if (idx < n) {
            int v = out[idx] + boff;
            out[idx] = v;
            cursor[idx] = v;
        }
    }
    if (blockIdx.x == 0 && t == 0) out[n] = ETOT;
}

__global__ __launch_bounds__(256) void k_scatter(const int* __restrict__ ei, int* cursor,
                                                 int* __restrict__ csr) {
    int id = blockIdx.x * 256 + threadIdx.x;
    if (id < NEDGE) {
        unsigned s = (unsigned)ei[id];
        unsigned d = (unsigned)ei[NEDGE + id];
        if (d < NODES) {
            int pos = atomicAdd(&cursor[d], 1);
            if ((unsigned)pos < ETOT) csr[pos] = (int)s;
        }
    } else if (id < ETOT) {
        int nn = id - NEDGE;
        int pos = atomicAdd(&cursor[nn], 1);
        if ((unsigned)pos < ETOT) csr[pos] = nn;  // self-loop
    }
}

// ---------------- small precomputed vectors ----------------
// wad1[k] = sum_c W1_dst[k][c]*a1_dst[c]   (128)
// wad2[c] = sum_j W2_dst[c][j]*a2_dst[j]   (64)
__global__ __launch_bounds__(128) void k_prep(const float* __restrict__ W1d, const float* __restrict__ a1d,
                                              const float* __restrict__ W2d, const float* __restrict__ a2d,
                                              float* wad1, float* wad2) {
    int t = threadIdx.x;
    if (t < FIN) {
        float acc = 0.f;
        for (int c = 0; c < C1; c++) acc = fmaf(W1d[t * C1 + c], a1d[c], acc);
        wad1[t] = acc;
    }
    if (t < C1) {
        wad2[t] = fmaf(W2d[t * 2], a2d[0], W2d[t * 2 + 1] * a2d[1]);
    }
}

// ---------------- GEMM1: hs1 = x@W1_src, ad1 = x@wad1, as1 = hs1@a1_src ----------------

__global__ __launch_bounds__(256) void k_gemm1(const float* __restrict__ x, const float* __restrict__ Ws,
                                               const float* __restrict__ wad, const float* __restrict__ a_src,
                                               float* __restrict__ hs, float* __restrict__ as_out,
                                               float* __restrict__ ad_out) {
    __shared__ float xt[FIN * 64];   // transposed [k][node], 32KB
    __shared__ float part[4][64];
    int t = threadIdx.x;
    int n0 = blockIdx.x * 64;
    // stage x tile (transposed)
    {
        int node_l = t >> 2, q = t & 3;
        bool valid = (n0 + node_l) < NODES;
        const float4* xrow = reinterpret_cast<const float4*>(x + (size_t)(n0 + node_l) * FIN);
        #pragma unroll
        for (int i = 0; i < 8; i++) {
            int k4 = q * 8 + i;
            float4 v = valid ? xrow[k4] : make_float4(0.f, 0.f, 0.f, 0.f);
            int kk = k4 * 4;
            xt[(kk + 0) * 64 + node_l] = v.x;
            xt[(kk + 1) * 64 + node_l] = v.y;
            xt[(kk + 2) * 64 + node_l] = v.z;
            xt[(kk + 3) * 64 + node_l] = v.w;
        }
    }
    __syncthreads();
    int lane = t & 63, cg = t >> 6;
    float acc[16];
    #pragma unroll
    for (int c = 0; c < 16; c++) acc[c] = 0.f;
    float adacc = 0.f;
    for (int k = 0; k < FIN; k++) {
        float xv = xt[k * 64 + lane];
        const float* wrow = Ws + k * C1 + cg * 16;
        #pragma unroll
        for (int c = 0; c < 16; c++) acc[c] = fmaf(xv, wrow[c], acc[c]);
        if (cg == 0) adacc = fmaf(xv, wad[k], adacc);
    }
    // as partial
    float asp = 0.f;
    #pragma unroll
    for (int c = 0; c < 16; c++) asp = fmaf(acc[c], a_src[cg * 16 + c], asp);
    part[cg][lane] = asp;
    int n = n0 + lane;
    if (n < NODES) {
        float4* hrow = reinterpret_cast<float4*>(hs + (size_t)n * C1 + cg * 16);
        #pragma unroll
        for (int i = 0; i < 4; i++)
            hrow[i] = make_float4(acc[i * 4], acc[i * 4 + 1], acc[i * 4 + 2], acc[i * 4 + 3]);
    }
    __syncthreads();
    if (cg == 0 && n < NODES) {
        as_out[n] = part[0][lane] + part[1][lane] + part[2][lane] + part[3][lane];
        ad_out[n] = adacc;
    }
}

// ---------------- aggregation layer 1: wave per node, lane = channel ----------------

__global__ __launch_bounds__(256) void k_agg1(const int* __restrict__ offs, const int* __restrict__ csr,
                                              const float* __restrict__ as1, const float* __restrict__ ad1,
                                              const float* __restrict__ hs1, const float* __restrict__ b1,
                                              float* __restrict__ h1) {
    int w = threadIdx.x >> 6, lane = threadIdx.x & 63;
    int node = blockIdx.x * 4 + w;
    if (node >= NODES) return;
    int e0 = offs[node], e1 = offs[node + 1];
    float adn = ad1[node];
    float lmax = -INFINITY;
    for (int e = e0 + lane; e < e1; e += 64) {
        float v = as1[csr[e]] + adn;
        v = v > 0.f ? v : NEG * v;
        lmax = fmaxf(lmax, v);
    }
    #pragma unroll
    for (int o = 32; o; o >>= 1) lmax = fmaxf(lmax, __shfl_xor(lmax, o));
    float m = lmax;
    float acc = 0.f, ssum = 0.f;
    for (int e = e0; e < e1; e++) {
        int s = csr[e];
        float v = as1[s] + adn;
        v = v > 0.f ? v : NEG * v;
        float p = __expf(v - m);
        ssum += p;
        acc = fmaf(p, hs1[(size_t)s * C1 + lane], acc);
    }
    h1[(size_t)node * C1 + lane] = acc / (ssum + 1e-16f) + b1[lane];
}

// ---------------- BN stats: deterministic per-block partials, NO atomics, NO memset ----------------

__global__ __launch_bounds__(256) void k_bnstats(const float* __restrict__ h1, float* __restrict__ bnpart) {
    __shared__ float ls[256], lq[256];
    int t = threadIdx.x;
    int c = t & 63, g = t >> 6;
    float s = 0.f, q = 0.f;
    for (int n = blockIdx.x * 4 + g; n < NODES; n += BNBLK * 4) {
        float v = h1[(size_t)n * C1 + c];
        s += v;
        q = fmaf(v, v, q);
    }
    ls[t] = s; lq[t] = q;
    __syncthreads();
    if (t < 64) {
        bnpart[(size_t)blockIdx.x * 128 + t]      = ls[t] + ls[t + 64] + ls[t + 128] + ls[t + 192];
        bnpart[(size_t)blockIdx.x * 128 + 64 + t] = lq[t] + lq[t + 64] + lq[t + 128] + lq[t + 192];
    }
}

__global__ __launch_bounds__(64) void k_bnfinal(const float* __restrict__ bnpart,
                                                const float* __restrict__ gamma, const float* __restrict__ beta,
                                                float* bnscale, float* bnshift) {
    int c = threadIdx.x;
    if (c < C1) {
        float s = 0.f, q = 0.f;
        for (int b = 0; b < BNBLK; b++) {
            s += bnpart[(size_t)b * 128 + c];
            q += bnpart[(size_t)b * 128 + 64 + c];
        }
        float mu = s * (1.0f / NODES);
        float var = q * (1.0f / NODES) - mu * mu;
        if (var < 0.f) var = 0.f;
        float rinv = 1.0f / sqrtf(var + BNEPS);
        float sc = gamma[c] * rinv;
        bnscale[c] = sc;
        bnshift[c] = beta[c] - mu * sc;
    }
}

// ---------------- BN apply + ReLU + GEMM2 (+alpha dots) ----------------

__global__ __launch_bounds__(256) void k_bngemm2(const float* __restrict__ h1, const float* __restrict__ bnscale,
                                                 const float* __restrict__ bnshift, const float* __restrict__ W2s,
                                                 const float* __restrict__ wad2, const float* __restrict__ a2s,
                                                 float* __restrict__ hs2, float* __restrict__ as2,
                                                 float* __restrict__ ad2) {
    int n = blockIdx.x * 256 + threadIdx.x;
    if (n >= NODES) return;
    const float4* hr = reinterpret_cast<const float4*>(h1 + (size_t)n * C1);
    float h0 = 0.f, h1v = 0.f, adv = 0.f;
    #pragma unroll
    for (int c4 = 0; c4 < 16; c4++) {
        float4 v = hr[c4];
        float vv[4] = {v.x, v.y, v.z, v.w};
        #pragma unroll
        for (int j = 0; j < 4; j++) {
            int c = c4 * 4 + j;
            float y = fmaf(vv[j], bnscale[c], bnshift[c]);
            y = fmaxf(y, 0.f);
            h0 = fmaf(y, W2s[c * 2 + 0], h0);
            h1v = fmaf(y, W2s[c * 2 + 1], h1v);
            adv = fmaf(y, wad2[c], adv);
        }
    }
    hs2[n * 2 + 0] = h0;
    hs2[n * 2 + 1] = h1v;
    as2[n] = fmaf(h0, a2s[0], h1v * a2s[1]);
    ad2[n] = adv;
}

// ---------------- aggregation layer 2: thread per node ----------------

__global__ __launch_bounds__(256) void k_agg2(const int* __restrict__ offs, const int* __restrict__ csr,
                                              const float* __restrict__ as2, const float* __restrict__ ad2,
                                              const float* __restrict__ hs2, const float* __restrict__ b2,
                                              float* __restrict__ out) {
    int n = blockIdx.x * 256 + threadIdx.x;
    if (n >= NODES) return;
    int e0 = offs[n], e1 = offs[n + 1];
    float adn = ad2[n];
    float m = -INFINITY;
    for (int e = e0; e < e1; e++) {
        float v = as2[csr[e]] + adn;
        v = v > 0.f ? v : NEG * v;
        m = fmaxf(m, v);
    }
    float ss = 0.f, A0 = 0.f, A1 = 0.f;
    const float2* h2 = reinterpret_cast<const float2*>(hs2);
    for (int e = e0; e < e1; e++) {
        int s = csr[e];
        float v = as2[s] + adn;
        v = v > 0.f ? v : NEG * v;
        float p = __expf(v - m);
        ss += p;
        float2 hv = h2[s];
        A0 = fmaf(p, hv.x, A0);
        A1 = fmaf(p, hv.y, A1);
    }
    float inv = 1.0f / (ss + 1e-16f);
    out[n * 2 + 0] = fmaf(A0, inv, b2[0]);
    out[n * 2 + 1] = fmaf(A1, inv, b2[1]);
}

// ---------------- host ----------------

static inline size_t align256(size_t x) { return (x + 255) & ~size_t(255); }

extern "C" void kernel_launch(void* const* d_in, const int* in_sizes, int n_in,
                              void* d_out, int out_size, void* d_ws, size_t ws_size,
                              hipStream_t stream) {
    const float* x     = (const float*)d_in[0];
    const int*   ei    = (const int*)d_in[1];
    const float* W1s   = (const float*)d_in[2];
    const float* W1d   = (const float*)d_in[3];
    const float* a1s   = (const float*)d_in[4];
    const float* a1d   = (const float*)d_in[5];
    const float* b1    = (const float*)d_in[6];
    const float* gamma = (const float*)d_in[7];
    const float* beta  = (const float*)d_in[8];
    const float* W2s   = (const float*)d_in[9];
    const float* W2d   = (const float*)d_in[10];
    const float* a2s   = (const float*)d_in[11];
    const float* a2d   = (const float*)d_in[12];
    const float* b2    = (const float*)d_in[13];
    float* out = (float*)d_out;

    char* w = (char*)d_ws;
    size_t off = 0;
    auto alloc = [&](size_t bytes) -> void* {
        void* p = w + off;
        off = align256(off + bytes);
        return p;
    };
    int* counts   = (int*)alloc((size_t)NODES * 4);
    int* offs     = (int*)alloc((size_t)(NODES + 1) * 4);
    int* cursor   = (int*)alloc((size_t)NODES * 4);
    int* bsums    = (int*)alloc(256 * 4);
    int* csr      = (int*)alloc((size_t)ETOT * 4);
    float* hs1    = (float*)alloc((size_t)NODES * C1 * 4);
    float* as1    = (float*)alloc((size_t)NODES * 4);
    float* ad1    = (float*)alloc((size_t)NODES * 4);
    float* h1     = (float*)alloc((size_t)NODES * C1 * 4);
    float* hs2    = (float*)alloc((size_t)NODES * 2 * 4);
    float* as2    = (float*)alloc((size_t)NODES * 4);
    float* ad2    = (float*)alloc((size_t)NODES * 4);
    float* wad1   = (float*)alloc(FIN * 4);
    float* wad2   = (float*)alloc(C1 * 4);
    float* bnpart = (float*)alloc((size_t)BNBLK * 128 * 4);  // per-block BN partials
    float* bnsc   = (float*)alloc(64 * 4);
    float* bnsh   = (float*)alloc(64 * 4);
    if (off > ws_size) return;  // insufficient workspace -> visible failure

    const int NB = (NODES + 1023) / 1024;  // 98

    k_init_counts<<<(NODES + 255) / 256, 256, 0, stream>>>(counts);
    k_count_edges<<<(NEDGE + 255) / 256, 256, 0, stream>>>(ei, counts);
    k_scan1<<<NB, 256, 0, stream>>>(counts, offs, bsums, NODES);
    k_scan2<<<1, 128, 0, stream>>>(bsums, NB);
    k_scan3<<<NB, 256, 0, stream>>>(offs, bsums, cursor, NODES);
    k_scatter<<<(ETOT + 255) / 256, 256, 0, stream>>>(ei, cursor, csr);
    k_prep<<<1, 128, 0, stream>>>(W1d, a1d, W2d, a2d, wad1, wad2);
    k_gemm1<<<(NODES + 63) / 64, 256, 0, stream>>>(x, W1s, wad1, a1s, hs1, as1, ad1);
    k_agg1<<<(NODES + 3) / 4, 256, 0, stream>>>(offs, csr, as1, ad1, hs1, b1, h1);
    k_bnstats<<<BNBLK, 256, 0, stream>>>(h1, bnpart);
    k_bnfinal<<<1, 64, 0, stream>>>(bnpart, gamma, beta, bnsc, bnsh);
    k_bngemm2<<<(NODES + 255) / 256, 256, 0, stream>>>(h1, bnsc, bnsh, W2s, wad2, a2s, hs2, as2, ad2);
    k_agg2<<<(NODES + 255) / 256, 256, 0, stream>>>(offs, csr, as2, ad2, hs2, b2, out);
}

// Round 3
// 485.579 us; speedup vs baseline: 1.2285x; 1.2285x over previous
//
#include <hip/hip_runtime.h>
#include <math.h>

#define NODES 100000
#define NEDGE 1600000
#define ETOT  (NEDGE + NODES)
#define FIN   128
#define C1    64
#define NEG   0.2f
#define BNEPS 1e-5f
#define BNBLK 256

// ---------------- CSR build ----------------

__global__ __launch_bounds__(256) void k_init_counts(int* counts) {
    int n = blockIdx.x * 256 + threadIdx.x;
    if (n < NODES) counts[n] = 1;   // self-loop
}

__global__ __launch_bounds__(256) void k_count_edges(const int* __restrict__ ei, int* counts) {
    int e = blockIdx.x * 256 + threadIdx.x;
    if (e < NEDGE) {
        unsigned d = (unsigned)ei[NEDGE + e];
        if (d < NODES) atomicAdd(&counts[d], 1);
    }
}

// exclusive scan, 1024 items/block (256 thr x 4)
__global__ __launch_bounds__(256) void k_scan1(const int* __restrict__ in, int* __restrict__ out,
                                               int* __restrict__ bsums, int n) {
    __shared__ int lds[256];
    int t = threadIdx.x;
    int base = blockIdx.x * 1024 + t * 4;
    int v0 = (base + 0) < n ? in[base + 0] : 0;
    int v1 = (base + 1) < n ? in[base + 1] : 0;
    int v2 = (base + 2) < n ? in[base + 2] : 0;
    int v3 = (base + 3) < n ? in[base + 3] : 0;
    int tot = v0 + v1 + v2 + v3;
    lds[t] = tot;
    __syncthreads();
    for (int o = 1; o < 256; o <<= 1) {
        int add = (t >= o) ? lds[t - o] : 0;
        __syncthreads();
        lds[t] += add;
        __syncthreads();
    }
    int excl = lds[t] - tot;
    if (base + 0 < n) out[base + 0] = excl;
    if (base + 1 < n) out[base + 1] = excl + v0;
    if (base + 2 < n) out[base + 2] = excl + v0 + v1;
    if (base + 3 < n) out[base + 3] = excl + v0 + v1 + v2;
    if (t == 255) bsums[blockIdx.x] = lds[255];
}

__global__ __launch_bounds__(128) void k_scan2(int* bsums, int nb) {
    __shared__ int lds[128];
    int t = threadIdx.x;
    int own = (t < nb) ? bsums[t] : 0;
    lds[t] = own;
    __syncthreads();
    for (int o = 1; o < 128; o <<= 1) {
        int add = (t >= o) ? lds[t - o] : 0;
        __syncthreads();
        lds[t] += add;
        __syncthreads();
    }
    if (t < nb) bsums[t] = lds[t] - own;  // exclusive
}

__global__ __launch_bounds__(256) void k_scan3(int* __restrict__ out, const int* __restrict__ bsums,
                                               int* __restrict__ cursor, int n) {
    int t = threadIdx.x;
    int base = blockIdx.x * 1024 + t * 4;
    int boff = bsums[blockIdx.x];
    #pragma unroll
    for (int i = 0; i < 4; i++) {
        int idx = base + i;
        if (idx < n) {
            int v = out[idx] + boff;
            out[idx] = v;
            cursor[idx] = v;
        }
    }
    if (blockIdx.x == 0 && t == 0) out[n] = ETOT;
}

__global__ __launch_bounds__(256) void k_scatter(const int* __restrict__ ei, int* cursor,
                                                 int* __restrict__ csr) {
    int id = blockIdx.x * 256 + threadIdx.x;
    if (id < NEDGE) {
        unsigned s = (unsigned)ei[id];
        unsigned d = (unsigned)ei[NEDGE + id];
        if (d < NODES) {
            int pos = atomicAdd(&cursor[d], 1);
            if ((unsigned)pos < ETOT) csr[pos] = (int)s;
        }
    } else if (id < ETOT) {
        int nn = id - NEDGE;
        int pos = atomicAdd(&cursor[nn], 1);
        if ((unsigned)pos < ETOT) csr[pos] = nn;  // self-loop
    }
}

// ---------------- small precomputed vectors ----------------

__global__ __launch_bounds__(128) void k_prep(const float* __restrict__ W1d, const float* __restrict__ a1d,
                                              const float* __restrict__ W2d, const float* __restrict__ a2d,
                                              float* wad1, float* wad2) {
    int t = threadIdx.x;
    if (t < FIN) {
        float acc = 0.f;
        for (int c = 0; c < C1; c++) acc = fmaf(W1d[t * C1 + c], a1d[c], acc);
        wad1[t] = acc;
    }
    if (t < C1) {
        wad2[t] = fmaf(W2d[t * 2], a2d[0], W2d[t * 2 + 1] * a2d[1]);
    }
}

// ---------------- GEMM1: hs1 = x@W1_src, ad1 = x@wad1, as1 = hs1@a1_src ----------------

__global__ __launch_bounds__(256) void k_gemm1(const float* __restrict__ x, const float* __restrict__ Ws,
                                               const float* __restrict__ wad, const float* __restrict__ a_src,
                                               float* __restrict__ hs, float* __restrict__ as_out,
                                               float* __restrict__ ad_out) {
    __shared__ float xt[FIN * 64];   // transposed [k][node], 32KB
    __shared__ float part[4][64];
    int t = threadIdx.x;
    int n0 = blockIdx.x * 64;
    {
        int node_l = t >> 2, q = t & 3;
        bool valid = (n0 + node_l) < NODES;
        const float4* xrow = reinterpret_cast<const float4*>(x + (size_t)(n0 + node_l) * FIN);
        #pragma unroll
        for (int i = 0; i < 8; i++) {
            int k4 = q * 8 + i;
            float4 v = valid ? xrow[k4] : make_float4(0.f, 0.f, 0.f, 0.f);
            int kk = k4 * 4;
            xt[(kk + 0) * 64 + node_l] = v.x;
            xt[(kk + 1) * 64 + node_l] = v.y;
            xt[(kk + 2) * 64 + node_l] = v.z;
            xt[(kk + 3) * 64 + node_l] = v.w;
        }
    }
    __syncthreads();
    int lane = t & 63, cg = t >> 6;
    float acc[16];
    #pragma unroll
    for (int c = 0; c < 16; c++) acc[c] = 0.f;
    float adacc = 0.f;
    for (int k = 0; k < FIN; k++) {
        float xv = xt[k * 64 + lane];
        const float* wrow = Ws + k * C1 + cg * 16;
        #pragma unroll
        for (int c = 0; c < 16; c++) acc[c] = fmaf(xv, wrow[c], acc[c]);
        if (cg == 0) adacc = fmaf(xv, wad[k], adacc);
    }
    float asp = 0.f;
    #pragma unroll
    for (int c = 0; c < 16; c++) asp = fmaf(acc[c], a_src[cg * 16 + c], asp);
    part[cg][lane] = asp;
    int n = n0 + lane;
    if (n < NODES) {
        float4* hrow = reinterpret_cast<float4*>(hs + (size_t)n * C1 + cg * 16);
        #pragma unroll
        for (int i = 0; i < 4; i++)
            hrow[i] = make_float4(acc[i * 4], acc[i * 4 + 1], acc[i * 4 + 2], acc[i * 4 + 3]);
    }
    __syncthreads();
    if (cg == 0 && n < NODES) {
        as_out[n] = part[0][lane] + part[1][lane] + part[2][lane] + part[3][lane];
        ad_out[n] = adacc;
    }
}

// ---------------- aggregation layer 1 ----------------
// wave per node; lane-parallel softmax (no segment-max: alpha = exp(e)/sum exp(e),
// identical math, |e| <~ 12 << 88 so no overflow; clamp 60 as guard);
// row-gather loop 4x unrolled for MLP, (s,p) broadcast via shfl.

__global__ __launch_bounds__(256) void k_agg1(const int* __restrict__ offs, const int* __restrict__ csr,
                                              const float* __restrict__ as1, const float* __restrict__ ad1,
                                              const float* __restrict__ hs1, const float* __restrict__ b1,
                                              float* __restrict__ h1) {
    int w = threadIdx.x >> 6, lane = threadIdx.x & 63;
    int node = blockIdx.x * 4 + w;
    if (node >= NODES) return;
    int e0 = offs[node], e1 = offs[node + 1];
    float adn = ad1[node];
    float acc0 = 0.f, acc1 = 0.f, acc2 = 0.f, acc3 = 0.f;
    float ssum = 0.f;
    for (int base = e0; base < e1; base += 64) {
        int cnt = e1 - base; if (cnt > 64) cnt = 64;
        bool valid = lane < cnt;
        int s = valid ? csr[base + lane] : 0;
        float v = valid ? (as1[s] + adn) : -INFINITY;
        v = v > 0.f ? v : NEG * v;            // lrelu; -inf stays -inf
        float p = __expf(fminf(v, 60.f));     // exp(-inf)=0 for invalid lanes
        ssum += p;
        int j = 0;
        for (; j + 4 <= cnt; j += 4) {
            int   s0 = __shfl(s, j),     s1 = __shfl(s, j + 1);
            int   s2 = __shfl(s, j + 2), s3 = __shfl(s, j + 3);
            float p0 = __shfl(p, j),     p1 = __shfl(p, j + 1);
            float p2 = __shfl(p, j + 2), p3 = __shfl(p, j + 3);
            acc0 = fmaf(p0, hs1[(size_t)s0 * C1 + lane], acc0);
            acc1 = fmaf(p1, hs1[(size_t)s1 * C1 + lane], acc1);
            acc2 = fmaf(p2, hs1[(size_t)s2 * C1 + lane], acc2);
            acc3 = fmaf(p3, hs1[(size_t)s3 * C1 + lane], acc3);
        }
        for (; j < cnt; j++) {
            int   sj = __shfl(s, j);
            float pj = __shfl(p, j);
            acc0 = fmaf(pj, hs1[(size_t)sj * C1 + lane], acc0);
        }
    }
    #pragma unroll
    for (int o = 32; o; o >>= 1) ssum += __shfl_xor(ssum, o);
    float acc = (acc0 + acc1) + (acc2 + acc3);
    h1[(size_t)node * C1 + lane] = acc / (ssum + 1e-16f) + b1[lane];
}

// ---------------- BN stats: deterministic per-block partials ----------------

__global__ __launch_bounds__(256) void k_bnstats(const float* __restrict__ h1, float* __restrict__ bnpart) {
    __shared__ float ls[256], lq[256];
    int t = threadIdx.x;
    int c = t & 63, g = t >> 6;
    float s = 0.f, q = 0.f;
    for (int n = blockIdx.x * 4 + g; n < NODES; n += BNBLK * 4) {
        float v = h1[(size_t)n * C1 + c];
        s += v;
        q = fmaf(v, v, q);
    }
    ls[t] = s; lq[t] = q;
    __syncthreads();
    if (t < 64) {
        bnpart[(size_t)blockIdx.x * 128 + t]      = ls[t] + ls[t + 64] + ls[t + 128] + ls[t + 192];
        bnpart[(size_t)blockIdx.x * 128 + 64 + t] = lq[t] + lq[t + 64] + lq[t + 128] + lq[t + 192];
    }
}

__global__ __launch_bounds__(64) void k_bnfinal(const float* __restrict__ bnpart,
                                                const float* __restrict__ gamma, const float* __restrict__ beta,
                                                float* bnscale, float* bnshift) {
    int c = threadIdx.x;
    if (c < C1) {
        float s = 0.f, q = 0.f;
        for (int b = 0; b < BNBLK; b++) {
            s += bnpart[(size_t)b * 128 + c];
            q += bnpart[(size_t)b * 128 + 64 + c];
        }
        float mu = s * (1.0f / NODES);
        float var = q * (1.0f / NODES) - mu * mu;
        if (var < 0.f) var = 0.f;
        float rinv = 1.0f / sqrtf(var + BNEPS);
        float sc = gamma[c] * rinv;
        bnscale[c] = sc;
        bnshift[c] = beta[c] - mu * sc;
    }
}

// ---------------- BN apply + ReLU + GEMM2 (+alpha dots) ----------------

__global__ __launch_bounds__(256) void k_bngemm2(const float* __restrict__ h1, const float* __restrict__ bnscale,
                                                 const float* __restrict__ bnshift, const float* __restrict__ W2s,
                                                 const float* __restrict__ wad2, const float* __restrict__ a2s,
                                                 float* __restrict__ hs2, float* __restrict__ as2,
                                                 float* __restrict__ ad2) {
    int n = blockIdx.x * 256 + threadIdx.x;
    if (n >= NODES) return;
    const float4* hr = reinterpret_cast<const float4*>(h1 + (size_t)n * C1);
    float h0 = 0.f, h1v = 0.f, adv = 0.f;
    #pragma unroll
    for (int c4 = 0; c4 < 16; c4++) {
        float4 v = hr[c4];
        float vv[4] = {v.x, v.y, v.z, v.w};
        #pragma unroll
        for (int j = 0; j < 4; j++) {
            int c = c4 * 4 + j;
            float y = fmaf(vv[j], bnscale[c], bnshift[c]);
            y = fmaxf(y, 0.f);
            h0 = fmaf(y, W2s[c * 2 + 0], h0);
            h1v = fmaf(y, W2s[c * 2 + 1], h1v);
            adv = fmaf(y, wad2[c], adv);
        }
    }
    hs2[n * 2 + 0] = h0;
    hs2[n * 2 + 1] = h1v;
    as2[n] = fmaf(h0, a2s[0], h1v * a2s[1]);
    ad2[n] = adv;
}

// ---------------- aggregation layer 2: wave per node, fully lane-parallel ----------------

__global__ __launch_bounds__(256) void k_agg2(const int* __restrict__ offs, const int* __restrict__ csr,
                                              const float* __restrict__ as2, const float* __restrict__ ad2,
                                              const float* __restrict__ hs2, const float* __restrict__ b2,
                                              float* __restrict__ out) {
    int w = threadIdx.x >> 6, lane = threadIdx.x & 63;
    int node = blockIdx.x * 4 + w;
    if (node >= NODES) return;
    int e0 = offs[node], e1 = offs[node + 1];
    float adn = ad2[node];
    float ssum = 0.f, A0 = 0.f, A1 = 0.f;
    const float2* h2 = reinterpret_cast<const float2*>(hs2);
    for (int base = e0; base < e1; base += 64) {
        int e = base + lane;
        bool valid = e < e1;
        int s = valid ? csr[e] : 0;
        float v = valid ? (as2[s] + adn) : -INFINITY;
        v = v > 0.f ? v : NEG * v;
        float p = __expf(fminf(v, 60.f));
        ssum += p;
        float2 hv = valid ? h2[s] : make_float2(0.f, 0.f);
        A0 = fmaf(p, hv.x, A0);
        A1 = fmaf(p, hv.y, A1);
    }
    #pragma unroll
    for (int o = 32; o; o >>= 1) {
        ssum += __shfl_xor(ssum, o);
        A0   += __shfl_xor(A0, o);
        A1   += __shfl_xor(A1, o);
    }
    if (lane == 0) {
        float inv = 1.0f / (ssum + 1e-16f);
        float2 r = make_float2(fmaf(A0, inv, b2[0]), fmaf(A1, inv, b2[1]));
        reinterpret_cast<float2*>(out)[node] = r;
    }
}

// ---------------- host ----------------

static inline size_t align256(size_t x) { return (x + 255) & ~size_t(255); }

extern "C" void kernel_launch(void* const* d_in, const int* in_sizes, int n_in,
                              void* d_out, int out_size, void* d_ws, size_t ws_size,
                              hipStream_t stream) {
    const float* x     = (const float*)d_in[0];
    const int*   ei    = (const int*)d_in[1];
    const float* W1s   = (const float*)d_in[2];
    const float* W1d   = (const float*)d_in[3];
    const float* a1s   = (const float*)d_in[4];
    const float* a1d   = (const float*)d_in[5];
    const float* b1    = (const float*)d_in[6];
    const float* gamma = (const float*)d_in[7];
    const float* beta  = (const float*)d_in[8];
    const float* W2s   = (const float*)d_in[9];
    const float* W2d   = (const float*)d_in[10];
    const float* a2s   = (const float*)d_in[11];
    const float* a2d   = (const float*)d_in[12];
    const float* b2    = (const float*)d_in[13];
    float* out = (float*)d_out;

    char* w = (char*)d_ws;
    size_t off = 0;
    auto alloc = [&](size_t bytes) -> void* {
        void* p = w + off;
        off = align256(off + bytes);
        return p;
    };
    int* counts   = (int*)alloc((size_t)NODES * 4);
    int* offs     = (int*)alloc((size_t)(NODES + 1) * 4);
    int* cursor   = (int*)alloc((size_t)NODES * 4);
    int* bsums    = (int*)alloc(256 * 4);
    int* csr      = (int*)alloc((size_t)ETOT * 4);
    float* hs1    = (float*)alloc((size_t)NODES * C1 * 4);
    float* as1    = (float*)alloc((size_t)NODES * 4);
    float* ad1    = (float*)alloc((size_t)NODES * 4);
    float* h1     = (float*)alloc((size_t)NODES * C1 * 4);
    float* hs2    = (float*)alloc((size_t)NODES * 2 * 4);
    float* as2    = (float*)alloc((size_t)NODES * 4);
    float* ad2    = (float*)alloc((size_t)NODES * 4);
    float* wad1   = (float*)alloc(FIN * 4);
    float* wad2   = (float*)alloc(C1 * 4);
    float* bnpart = (float*)alloc((size_t)BNBLK * 128 * 4);
    float* bnsc   = (float*)alloc(64 * 4);
    float* bnsh   = (float*)alloc(64 * 4);
    if (off > ws_size) return;

    const int NB = (NODES + 1023) / 1024;  // 98

    k_init_counts<<<(NODES + 255) / 256, 256, 0, stream>>>(counts);
    k_count_edges<<<(NEDGE + 255) / 256, 256, 0, stream>>>(ei, counts);
    k_scan1<<<NB, 256, 0, stream>>>(counts, offs, bsums, NODES);
    k_scan2<<<1, 128, 0, stream>>>(bsums, NB);
    k_scan3<<<NB, 256, 0, stream>>>(offs, bsums, cursor, NODES);
    k_scatter<<<(ETOT + 255) / 256, 256, 0, stream>>>(ei, cursor, csr);
    k_prep<<<1, 128, 0, stream>>>(W1d, a1d, W2d, a2d, wad1, wad2);
    k_gemm1<<<(NODES + 63) / 64, 256, 0, stream>>>(x, W1s, wad1, a1s, hs1, as1, ad1);
    k_agg1<<<(NODES + 3) / 4, 256, 0, stream>>>(offs, csr, as1, ad1, hs1, b1, h1);
    k_bnstats<<<BNBLK, 256, 0, stream>>>(h1, bnpart);
    k_bnfinal<<<1, 64, 0, stream>>>(bnpart, gamma, beta, bnsc, bnsh);
    k_bngemm2<<<(NODES + 255) / 256, 256, 0, stream>>>(h1, bnsc, bnsh, W2s, wad2, a2s, hs2, as2, ad2);
    k_agg2<<<(NODES + 3) / 4, 256, 0, stream>>>(offs, csr, as2, ad2, hs2, b2, out);
}

// Round 4
// 307.022 us; speedup vs baseline: 1.9429x; 1.5816x over previous
//
#include <hip/hip_runtime.h>
#include <math.h>

#define NODES 100000
#define NEDGE 1600000
#define ETOT  (NEDGE + NODES)
#define FIN   128
#define C1    64
#define NEG   0.2f
#define BNEPS 1e-5f
#define BNBLK 256

#define BK     512                         // nodes per bucket
#define NBUCK  ((NODES + BK - 1) / BK)     // 196
#define PCAP   12288                       // per-bucket edge capacity (mean 8673, +38 sigma)
#define PTILE  4096                        // edges per k_part block

// ---------------- bucketed CSR build ----------------

__global__ __launch_bounds__(256) void k_zero256(int* p) {
    p[threadIdx.x] = 0;
}

// P1: partition edges into buckets by dst>>9; pack src | (dst&511)<<17
__global__ __launch_bounds__(256) void k_part(const int* __restrict__ ei, int* bcur,
                                              unsigned* __restrict__ tmp) {
    __shared__ int hist[256], hbase[256], run[256];
    int t = threadIdx.x;
    hist[t] = 0; run[t] = 0;
    __syncthreads();
    const int* srcs = ei;
    const int* dsts = ei + NEDGE;
    int e_base = blockIdx.x * PTILE;
    unsigned pack[16];
    int bkt[16];
    #pragma unroll
    for (int i = 0; i < 16; i++) {
        int e = e_base + i * 256 + t;
        bool valid = e < NEDGE;
        int s = valid ? srcs[e] : 0;
        int d = valid ? dsts[e] : 0;
        if ((unsigned)d >= NODES || (unsigned)s >= NODES) valid = false;
        bkt[i] = valid ? (d >> 9) : -1;
        pack[i] = (unsigned)s | ((unsigned)(d & (BK - 1)) << 17);
        if (valid) atomicAdd(&hist[bkt[i]], 1);
    }
    __syncthreads();
    hbase[t] = hist[t] ? atomicAdd(&bcur[t], hist[t]) : 0;
    __syncthreads();
    #pragma unroll
    for (int i = 0; i < 16; i++) {
        if (bkt[i] >= 0) {
            int slot = atomicAdd(&run[bkt[i]], 1) + hbase[bkt[i]];
            if (slot < PCAP) tmp[(size_t)bkt[i] * PCAP + slot] = pack[i];
        }
    }
}

// exclusive scan of 256 bucket totals
__global__ __launch_bounds__(256) void k_bscan(const int* __restrict__ bcur, int* __restrict__ bbase) {
    __shared__ int lds[256];
    int t = threadIdx.x;
    int own = bcur[t];
    lds[t] = own;
    __syncthreads();
    for (int o = 1; o < 256; o <<= 1) {
        int add = (t >= o) ? lds[t - o] : 0;
        __syncthreads();
        lds[t] += add;
        __syncthreads();
    }
    bbase[t] = lds[t] - own;
}

// P2: per bucket: per-node counts -> local scan (offs) -> LDS scatter -> coalesced csr write
__global__ __launch_bounds__(256) void k_build(const unsigned* __restrict__ tmp, const int* __restrict__ bcur,
                                               const int* __restrict__ bbase, int* __restrict__ offs,
                                               int* __restrict__ csr) {
    __shared__ int cnt[BK];        // per-node edge count, then cursor
    __shared__ int ps[256];        // pair-sum scan
    __shared__ int stage[PCAP + BK];
    int t = threadIdx.x;
    int b = blockIdx.x;
    int ecnt = bcur[b]; if (ecnt > PCAP) ecnt = PCAP;
    int csrbase = bbase[b] + BK * b;   // all earlier buckets have BK valid nodes (self-loops)
    const unsigned* ebuf = tmp + (size_t)b * PCAP;

    cnt[t] = 0; cnt[t + 256] = 0;
    __syncthreads();
    for (int e = t; e < ecnt; e += 256) {
        int dl = (ebuf[e] >> 17) & (BK - 1);
        atomicAdd(&cnt[dl], 1);
    }
    __syncthreads();
    // local exclusive scan over 512 counts (+1 self-loop per valid node)
    int i0 = 2 * t, i1 = 2 * t + 1;
    int g0 = b * BK + i0, g1 = b * BK + i1;
    int c0 = cnt[i0] + (g0 < NODES ? 1 : 0);
    int c1 = cnt[i1] + (g1 < NODES ? 1 : 0);
    int own = c0 + c1;
    ps[t] = own;
    __syncthreads();
    for (int o = 1; o < 256; o <<= 1) {
        int add = (t >= o) ? ps[t - o] : 0;
        __syncthreads();
        ps[t] += add;
        __syncthreads();
    }
    int excl0 = ps[t] - own;
    int excl1 = excl0 + c0;
    int total = ps[255];
    __syncthreads();
    // cursors + self-loops + offs
    if (g0 < NODES) {
        stage[excl0] = g0;
        cnt[i0] = excl0 + 1;
        offs[g0] = csrbase + excl0;
    }
    if (g1 < NODES) {
        stage[excl1] = g1;
        cnt[i1] = excl1 + 1;
        offs[g1] = csrbase + excl1;
    }
    if (b == NBUCK - 1 && t == 0) offs[NODES] = ETOT;
    __syncthreads();
    for (int e = t; e < ecnt; e += 256) {
        unsigned p = ebuf[e];
        int dl = (p >> 17) & (BK - 1);
        int slot = atomicAdd(&cnt[dl], 1);
        stage[slot] = (int)(p & 0x1FFFFu);
    }
    __syncthreads();
    for (int j = t; j < total; j += 256) csr[csrbase + j] = stage[j];
}

// ---------------- small precomputed vectors ----------------

__global__ __launch_bounds__(128) void k_prep(const float* __restrict__ W1d, const float* __restrict__ a1d,
                                              const float* __restrict__ W2d, const float* __restrict__ a2d,
                                              float* wad1, float* wad2) {
    int t = threadIdx.x;
    if (t < FIN) {
        float acc = 0.f;
        for (int c = 0; c < C1; c++) acc = fmaf(W1d[t * C1 + c], a1d[c], acc);
        wad1[t] = acc;
    }
    if (t < C1) {
        wad2[t] = fmaf(W2d[t * 2], a2d[0], W2d[t * 2 + 1] * a2d[1]);
    }
}

// ---------------- GEMM1: hs1 = x@W1_src, ad1 = x@wad1, as1 = hs1@a1_src ----------------

__global__ __launch_bounds__(256) void k_gemm1(const float* __restrict__ x, const float* __restrict__ Ws,
                                               const float* __restrict__ wad, const float* __restrict__ a_src,
                                               float* __restrict__ hs, float* __restrict__ as_out,
                                               float* __restrict__ ad_out) {
    __shared__ float xt[FIN * 64];   // transposed [k][node], 32KB
    __shared__ float part[4][64];
    int t = threadIdx.x;
    int n0 = blockIdx.x * 64;
    {
        int node_l = t >> 2, q = t & 3;
        bool valid = (n0 + node_l) < NODES;
        const float4* xrow = reinterpret_cast<const float4*>(x + (size_t)(n0 + node_l) * FIN);
        #pragma unroll
        for (int i = 0; i < 8; i++) {
            int k4 = q * 8 + i;
            float4 v = valid ? xrow[k4] : make_float4(0.f, 0.f, 0.f, 0.f);
            int kk = k4 * 4;
            xt[(kk + 0) * 64 + node_l] = v.x;
            xt[(kk + 1) * 64 + node_l] = v.y;
            xt[(kk + 2) * 64 + node_l] = v.z;
            xt[(kk + 3) * 64 + node_l] = v.w;
        }
    }
    __syncthreads();
    int lane = t & 63, cg = t >> 6;
    float acc[16];
    #pragma unroll
    for (int c = 0; c < 16; c++) acc[c] = 0.f;
    float adacc = 0.f;
    for (int k = 0; k < FIN; k++) {
        float xv = xt[k * 64 + lane];
        const float* wrow = Ws + k * C1 + cg * 16;
        #pragma unroll
        for (int c = 0; c < 16; c++) acc[c] = fmaf(xv, wrow[c], acc[c]);
        if (cg == 0) adacc = fmaf(xv, wad[k], adacc);
    }
    float asp = 0.f;
    #pragma unroll
    for (int c = 0; c < 16; c++) asp = fmaf(acc[c], a_src[cg * 16 + c], asp);
    part[cg][lane] = asp;
    int n = n0 + lane;
    if (n < NODES) {
        float4* hrow = reinterpret_cast<float4*>(hs + (size_t)n * C1 + cg * 16);
        #pragma unroll
        for (int i = 0; i < 4; i++)
            hrow[i] = make_float4(acc[i * 4], acc[i * 4 + 1], acc[i * 4 + 2], acc[i * 4 + 3]);
    }
    __syncthreads();
    if (cg == 0 && n < NODES) {
        as_out[n] = part[0][lane] + part[1][lane] + part[2][lane] + part[3][lane];
        ad_out[n] = adacc;
    }
}

// ---------------- aggregation layer 1 ----------------
// wave per node; lane-parallel softmax (alpha = exp(e)/sum exp(e), max dropped
// algebraically; |e| <~ 12 << 88, clamp 60 as guard); 4x-unrolled row gathers.

__global__ __launch_bounds__(256) void k_agg1(const int* __restrict__ offs, const int* __restrict__ csr,
                                              const float* __restrict__ as1, const float* __restrict__ ad1,
                                              const float* __restrict__ hs1, const float* __restrict__ b1,
                                              float* __restrict__ h1) {
    int w = threadIdx.x >> 6, lane = threadIdx.x & 63;
    int node = blockIdx.x * 4 + w;
    if (node >= NODES) return;
    int e0 = offs[node], e1 = offs[node + 1];
    float adn = ad1[node];
    float acc0 = 0.f, acc1 = 0.f, acc2 = 0.f, acc3 = 0.f;
    float ssum = 0.f;
    for (int base = e0; base < e1; base += 64) {
        int cnt = e1 - base; if (cnt > 64) cnt = 64;
        bool valid = lane < cnt;
        int s = valid ? csr[base + lane] : 0;
        float v = valid ? (as1[s] + adn) : -INFINITY;
        v = v > 0.f ? v : NEG * v;
        float p = __expf(fminf(v, 60.f));
        ssum += p;
        int j = 0;
        for (; j + 4 <= cnt; j += 4) {
            int   s0 = __shfl(s, j),     s1 = __shfl(s, j + 1);
            int   s2 = __shfl(s, j + 2), s3 = __shfl(s, j + 3);
            float p0 = __shfl(p, j),     p1 = __shfl(p, j + 1);
            float p2 = __shfl(p, j + 2), p3 = __shfl(p, j + 3);
            acc0 = fmaf(p0, hs1[(size_t)s0 * C1 + lane], acc0);
            acc1 = fmaf(p1, hs1[(size_t)s1 * C1 + lane], acc1);
            acc2 = fmaf(p2, hs1[(size_t)s2 * C1 + lane], acc2);
            acc3 = fmaf(p3, hs1[(size_t)s3 * C1 + lane], acc3);
        }
        for (; j < cnt; j++) {
            int   sj = __shfl(s, j);
            float pj = __shfl(p, j);
            acc0 = fmaf(pj, hs1[(size_t)sj * C1 + lane], acc0);
        }
    }
    #pragma unroll
    for (int o = 32; o; o >>= 1) ssum += __shfl_xor(ssum, o);
    float acc = (acc0 + acc1) + (acc2 + acc3);
    h1[(size_t)node * C1 + lane] = acc / (ssum + 1e-16f) + b1[lane];
}

// ---------------- BN stats: deterministic per-block partials ----------------

__global__ __launch_bounds__(256) void k_bnstats(const float* __restrict__ h1, float* __restrict__ bnpart) {
    __shared__ float ls[256], lq[256];
    int t = threadIdx.x;
    int c = t & 63, g = t >> 6;
    float s = 0.f, q = 0.f;
    for (int n = blockIdx.x * 4 + g; n < NODES; n += BNBLK * 4) {
        float v = h1[(size_t)n * C1 + c];
        s += v;
        q = fmaf(v, v, q);
    }
    ls[t] = s; lq[t] = q;
    __syncthreads();
    if (t < 64) {
        bnpart[(size_t)blockIdx.x * 128 + t]      = ls[t] + ls[t + 64] + ls[t + 128] + ls[t + 192];
        bnpart[(size_t)blockIdx.x * 128 + 64 + t] = lq[t] + lq[t + 64] + lq[t + 128] + lq[t + 192];
    }
}

__global__ __launch_bounds__(64) void k_bnfinal(const float* __restrict__ bnpart,
                                                const float* __restrict__ gamma, const float* __restrict__ beta,
                                                float* bnscale, float* bnshift) {
    int c = threadIdx.x;
    if (c < C1) {
        float s = 0.f, q = 0.f;
        for (int b = 0; b < BNBLK; b++) {
            s += bnpart[(size_t)b * 128 + c];
            q += bnpart[(size_t)b * 128 + 64 + c];
        }
        float mu = s * (1.0f / NODES);
        float var = q * (1.0f / NODES) - mu * mu;
        if (var < 0.f) var = 0.f;
        float rinv = 1.0f / sqrtf(var + BNEPS);
        float sc = gamma[c] * rinv;
        bnscale[c] = sc;
        bnshift[c] = beta[c] - mu * sc;
    }
}

// ---------------- BN apply + ReLU + GEMM2 (+alpha dots) ----------------

__global__ __launch_bounds__(256) void k_bngemm2(const float* __restrict__ h1, const float* __restrict__ bnscale,
                                                 const float* __restrict__ bnshift, const float* __restrict__ W2s,
                                                 const float* __restrict__ wad2, const float* __restrict__ a2s,
                                                 float* __restrict__ hs2, float* __restrict__ as2,
                                                 float* __restrict__ ad2) {
    int n = blockIdx.x * 256 + threadIdx.x;
    if (n >= NODES) return;
    const float4* hr = reinterpret_cast<const float4*>(h1 + (size_t)n * C1);
    float h0 = 0.f, h1v = 0.f, adv = 0.f;
    #pragma unroll
    for (int c4 = 0; c4 < 16; c4++) {
        float4 v = hr[c4];
        float vv[4] = {v.x, v.y, v.z, v.w};
        #pragma unroll
        for (int j = 0; j < 4; j++) {
            int c = c4 * 4 + j;
            float y = fmaf(vv[j], bnscale[c], bnshift[c]);
            y = fmaxf(y, 0.f);
            h0 = fmaf(y, W2s[c * 2 + 0], h0);
            h1v = fmaf(y, W2s[c * 2 + 1], h1v);
            adv = fmaf(y, wad2[c], adv);
        }
    }
    hs2[n * 2 + 0] = h0;
    hs2[n * 2 + 1] = h1v;
    as2[n] = fmaf(h0, a2s[0], h1v * a2s[1]);
    ad2[n] = adv;
}

// ---------------- aggregation layer 2: wave per node, fully lane-parallel ----------------

__global__ __launch_bounds__(256) void k_agg2(const int* __restrict__ offs, const int* __restrict__ csr,
                                              const float* __restrict__ as2, const float* __restrict__ ad2,
                                              const float* __restrict__ hs2, const float* __restrict__ b2,
                                              float* __restrict__ out) {
    int w = threadIdx.x >> 6, lane = threadIdx.x & 63;
    int node = blockIdx.x * 4 + w;
    if (node >= NODES) return;
    int e0 = offs[node], e1 = offs[node + 1];
    float adn = ad2[node];
    float ssum = 0.f, A0 = 0.f, A1 = 0.f;
    const float2* h2 = reinterpret_cast<const float2*>(hs2);
    for (int base = e0; base < e1; base += 64) {
        int e = base + lane;
        bool valid = e < e1;
        int s = valid ? csr[e] : 0;
        float v = valid ? (as2[s] + adn) : -INFINITY;
        v = v > 0.f ? v : NEG * v;
        float p = __expf(fminf(v, 60.f));
        ssum += p;
        float2 hv = valid ? h2[s] : make_float2(0.f, 0.f);
        A0 = fmaf(p, hv.x, A0);
        A1 = fmaf(p, hv.y, A1);
    }
    #pragma unroll
    for (int o = 32; o; o >>= 1) {
        ssum += __shfl_xor(ssum, o);
        A0   += __shfl_xor(A0, o);
        A1   += __shfl_xor(A1, o);
    }
    if (lane == 0) {
        float inv = 1.0f / (ssum + 1e-16f);
        float2 r = make_float2(fmaf(A0, inv, b2[0]), fmaf(A1, inv, b2[1]));
        reinterpret_cast<float2*>(out)[node] = r;
    }
}

// ---------------- host ----------------

static inline size_t align256(size_t x) { return (x + 255) & ~size_t(255); }

extern "C" void kernel_launch(void* const* d_in, const int* in_sizes, int n_in,
                              void* d_out, int out_size, void* d_ws, size_t ws_size,
                              hipStream_t stream) {
    const float* x     = (const float*)d_in[0];
    const int*   ei    = (const int*)d_in[1];
    const float* W1s   = (const float*)d_in[2];
    const float* W1d   = (const float*)d_in[3];
    const float* a1s   = (const float*)d_in[4];
    const float* a1d   = (const float*)d_in[5];
    const float* b1    = (const float*)d_in[6];
    const float* gamma = (const float*)d_in[7];
    const float* beta  = (const float*)d_in[8];
    const float* W2s   = (const float*)d_in[9];
    const float* W2d   = (const float*)d_in[10];
    const float* a2s   = (const float*)d_in[11];
    const float* a2d   = (const float*)d_in[12];
    const float* b2    = (const float*)d_in[13];
    float* out = (float*)d_out;

    char* w = (char*)d_ws;
    size_t off = 0;
    auto alloc = [&](size_t bytes) -> void* {
        void* p = w + off;
        off = align256(off + bytes);
        return p;
    };
    int* offs     = (int*)alloc((size_t)(NODES + 1) * 4);
    int* bcur     = (int*)alloc(256 * 4);
    int* bbase    = (int*)alloc(256 * 4);
    int* csr      = (int*)alloc((size_t)ETOT * 4);
    float* hs1    = (float*)alloc((size_t)NODES * C1 * 4);
    float* as1    = (float*)alloc((size_t)NODES * 4);
    float* ad1    = (float*)alloc((size_t)NODES * 4);
    float* h1     = (float*)alloc((size_t)NODES * C1 * 4);   // also aliases csr_tmp (see below)
    float* hs2    = (float*)alloc((size_t)NODES * 2 * 4);
    float* as2    = (float*)alloc((size_t)NODES * 4);
    float* ad2    = (float*)alloc((size_t)NODES * 4);
    float* wad1   = (float*)alloc(FIN * 4);
    float* wad2   = (float*)alloc(C1 * 4);
    float* bnpart = (float*)alloc((size_t)BNBLK * 128 * 4);
    float* bnsc   = (float*)alloc(64 * 4);
    float* bnsh   = (float*)alloc(64 * 4);
    if (off > ws_size) return;

    // csr_tmp (NBUCK*PCAP ints = 9.7MB) aliases h1 (25.6MB): k_build fully consumes
    // csr_tmp before k_agg1 produces h1 (in-order stream => safe).
    unsigned* csr_tmp = (unsigned*)h1;

    k_zero256<<<1, 256, 0, stream>>>(bcur);
    k_part<<<(NEDGE + PTILE - 1) / PTILE, 256, 0, stream>>>(ei, bcur, csr_tmp);
    k_bscan<<<1, 256, 0, stream>>>(bcur, bbase);
    k_build<<<NBUCK, 256, 0, stream>>>(csr_tmp, bcur, bbase, offs, csr);
    k_prep<<<1, 128, 0, stream>>>(W1d, a1d, W2d, a2d, wad1, wad2);
    k_gemm1<<<(NODES + 63) / 64, 256, 0, stream>>>(x, W1s, wad1, a1s, hs1, as1, ad1);
    k_agg1<<<(NODES + 3) / 4, 256, 0, stream>>>(offs, csr, as1, ad1, hs1, b1, h1);
    k_bnstats<<<BNBLK, 256, 0, stream>>>(h1, bnpart);
    k_bnfinal<<<1, 64, 0, stream>>>(bnpart, gamma, beta, bnsc, bnsh);
    k_bngemm2<<<(NODES + 255) / 256, 256, 0, stream>>>(h1, bnsc, bnsh, W2s, wad2, a2s, hs2, as2, ad2);
    k_agg2<<<(NODES + 3) / 4, 256, 0, stream>>>(offs, csr, as2, ad2, hs2, b2, out);
}

// Round 5
// 253.390 us; speedup vs baseline: 2.3542x; 1.2117x over previous
//
#include <hip/hip_runtime.h>
#include <math.h>

#define NODES 100000
#define NEDGE 1600000
#define ETOT  (NEDGE + NODES)
#define FIN   128
#define C1    64
#define NEG   0.2f
#define BNEPS 1e-5f
#define BNBLK 256

#define BK     512                         // nodes per bucket
#define NBUCK  ((NODES + BK - 1) / BK)     // 196
#define PCAP   12288                       // per-bucket edge capacity (mean 8673, +38 sigma)
#define PTILE  4096                        // edges per k_part block

// ---------------- bucketed CSR build ----------------

__global__ __launch_bounds__(256) void k_zero256(int* p) {
    p[threadIdx.x] = 0;
}

// P1: partition edges into buckets by dst>>9; pack src | (dst&511)<<17
__global__ __launch_bounds__(256) void k_part(const int* __restrict__ ei, int* bcur,
                                              unsigned* __restrict__ tmp) {
    __shared__ int hist[256], hbase[256], run[256];
    int t = threadIdx.x;
    hist[t] = 0; run[t] = 0;
    __syncthreads();
    const int* srcs = ei;
    const int* dsts = ei + NEDGE;
    int e_base = blockIdx.x * PTILE;
    unsigned pack[16];
    int bkt[16];
    #pragma unroll
    for (int i = 0; i < 16; i++) {
        int e = e_base + i * 256 + t;
        bool valid = e < NEDGE;
        int s = valid ? srcs[e] : 0;
        int d = valid ? dsts[e] : 0;
        if ((unsigned)d >= NODES || (unsigned)s >= NODES) valid = false;
        bkt[i] = valid ? (d >> 9) : -1;
        pack[i] = (unsigned)s | ((unsigned)(d & (BK - 1)) << 17);
        if (valid) atomicAdd(&hist[bkt[i]], 1);
    }
    __syncthreads();
    hbase[t] = hist[t] ? atomicAdd(&bcur[t], hist[t]) : 0;
    __syncthreads();
    #pragma unroll
    for (int i = 0; i < 16; i++) {
        if (bkt[i] >= 0) {
            int slot = atomicAdd(&run[bkt[i]], 1) + hbase[bkt[i]];
            if (slot < PCAP) tmp[(size_t)bkt[i] * PCAP + slot] = pack[i];
        }
    }
}

// exclusive scan of 256 bucket totals
__global__ __launch_bounds__(256) void k_bscan(const int* __restrict__ bcur, int* __restrict__ bbase) {
    __shared__ int lds[256];
    int t = threadIdx.x;
    int own = bcur[t];
    lds[t] = own;
    __syncthreads();
    for (int o = 1; o < 256; o <<= 1) {
        int add = (t >= o) ? lds[t - o] : 0;
        __syncthreads();
        lds[t] += add;
        __syncthreads();
    }
    bbase[t] = lds[t] - own;
}

// P2: per bucket: per-node counts -> local scan (offs) -> LDS scatter -> coalesced csr write
__global__ __launch_bounds__(256) void k_build(const unsigned* __restrict__ tmp, const int* __restrict__ bcur,
                                               const int* __restrict__ bbase, int* __restrict__ offs,
                                               int* __restrict__ csr) {
    __shared__ int cnt[BK];        // per-node edge count, then cursor
    __shared__ int ps[256];        // pair-sum scan
    __shared__ int stage[PCAP + BK];
    int t = threadIdx.x;
    int b = blockIdx.x;
    int ecnt = bcur[b]; if (ecnt > PCAP) ecnt = PCAP;
    int csrbase = bbase[b] + BK * b;   // all earlier buckets have BK valid nodes (self-loops)
    const unsigned* ebuf = tmp + (size_t)b * PCAP;

    cnt[t] = 0; cnt[t + 256] = 0;
    __syncthreads();
    for (int e = t; e < ecnt; e += 256) {
        int dl = (ebuf[e] >> 17) & (BK - 1);
        atomicAdd(&cnt[dl], 1);
    }
    __syncthreads();
    // local exclusive scan over 512 counts (+1 self-loop per valid node)
    int i0 = 2 * t, i1 = 2 * t + 1;
    int g0 = b * BK + i0, g1 = b * BK + i1;
    int c0 = cnt[i0] + (g0 < NODES ? 1 : 0);
    int c1 = cnt[i1] + (g1 < NODES ? 1 : 0);
    int own = c0 + c1;
    ps[t] = own;
    __syncthreads();
    for (int o = 1; o < 256; o <<= 1) {
        int add = (t >= o) ? ps[t - o] : 0;
        __syncthreads();
        ps[t] += add;
        __syncthreads();
    }
    int excl0 = ps[t] - own;
    int excl1 = excl0 + c0;
    int total = ps[255];
    __syncthreads();
    // cursors + self-loops + offs
    if (g0 < NODES) {
        stage[excl0] = g0;
        cnt[i0] = excl0 + 1;
        offs[g0] = csrbase + excl0;
    }
    if (g1 < NODES) {
        stage[excl1] = g1;
        cnt[i1] = excl1 + 1;
        offs[g1] = csrbase + excl1;
    }
    if (b == NBUCK - 1 && t == 0) offs[NODES] = ETOT;
    __syncthreads();
    for (int e = t; e < ecnt; e += 256) {
        unsigned p = ebuf[e];
        int dl = (p >> 17) & (BK - 1);
        int slot = atomicAdd(&cnt[dl], 1);
        stage[slot] = (int)(p & 0x1FFFFu);
    }
    __syncthreads();
    for (int j = t; j < total; j += 256) csr[csrbase + j] = stage[j];
}

// ---------------- small precomputed vectors ----------------

__global__ __launch_bounds__(128) void k_prep(const float* __restrict__ W1d, const float* __restrict__ a1d,
                                              const float* __restrict__ W2d, const float* __restrict__ a2d,
                                              float* wad1, float* wad2) {
    int t = threadIdx.x;
    if (t < FIN) {
        float acc = 0.f;
        for (int c = 0; c < C1; c++) acc = fmaf(W1d[t * C1 + c], a1d[c], acc);
        wad1[t] = acc;
    }
    if (t < C1) {
        wad2[t] = fmaf(W2d[t * 2], a2d[0], W2d[t * 2 + 1] * a2d[1]);
    }
}

// ---------------- GEMM1: hs1 = x@W1_src, ad1 = x@wad1, as1 = hs1@a1_src ----------------
// All K-loop operands in LDS/registers: xs[node][k4] float4 (stride 33 to spread
// banks at the b128 bandwidth floor), Wt[k][c] staged once (stride 68; col 64 = wad),
// inner W reads are wave-uniform broadcasts. 64 FMA per 4-k chunk per thread.

__global__ __launch_bounds__(256) void k_gemm1(const float* __restrict__ x, const float* __restrict__ Ws,
                                               const float* __restrict__ wad, const float* __restrict__ a_src,
                                               float* __restrict__ hs, float* __restrict__ as_out,
                                               float* __restrict__ ad_out) {
    __shared__ float4 xs[64 * 33];     // 33.8 KB
    __shared__ float  Wt[128 * 68];    // 34.8 KB
    __shared__ float  part[4][64];
    int t = threadIdx.x;
    int lane = t & 63, cg = t >> 6;
    int n0 = blockIdx.x * 64;

    // stage x tile: thread handles node=lane, float4-chunk range [cg*8, cg*8+8)
    {
        int node_g = n0 + lane;
        bool v = node_g < NODES;
        const float4* xr = reinterpret_cast<const float4*>(x + (size_t)node_g * FIN);
        #pragma unroll
        for (int i = 0; i < 8; i++) {
            int j = cg * 8 + i;
            xs[lane * 33 + j] = v ? xr[j] : make_float4(0.f, 0.f, 0.f, 0.f);
        }
    }
    // stage W: thread -> row k=t>>1, half q=t&1 (8 float4 each); col 64 = wad
    {
        int k = t >> 1, q = t & 1;
        const float4* wr = reinterpret_cast<const float4*>(Ws + (size_t)k * C1);
        float4* dst = reinterpret_cast<float4*>(&Wt[k * 68]);   // 272B row stride, 16B aligned
        #pragma unroll
        for (int i = 0; i < 8; i++) dst[q * 8 + i] = wr[q * 8 + i];
        if (t < FIN) Wt[t * 68 + 64] = wad[t];
    }
    __syncthreads();

    float acc[16];
    #pragma unroll
    for (int c = 0; c < 16; c++) acc[c] = 0.f;
    float adacc = 0.f;
    for (int k4 = 0; k4 < 32; k4++) {
        float4 xv = xs[lane * 33 + k4];
        #pragma unroll
        for (int kk = 0; kk < 4; kk++) {
            int k = k4 * 4 + kk;
            float xk = (kk == 0) ? xv.x : (kk == 1) ? xv.y : (kk == 2) ? xv.z : xv.w;
            const float4* wr = reinterpret_cast<const float4*>(&Wt[k * 68 + cg * 16]);
            float4 w0 = wr[0], w1 = wr[1], w2 = wr[2], w3 = wr[3];
            acc[ 0] = fmaf(xk, w0.x, acc[ 0]); acc[ 1] = fmaf(xk, w0.y, acc[ 1]);
            acc[ 2] = fmaf(xk, w0.z, acc[ 2]); acc[ 3] = fmaf(xk, w0.w, acc[ 3]);
            acc[ 4] = fmaf(xk, w1.x, acc[ 4]); acc[ 5] = fmaf(xk, w1.y, acc[ 5]);
            acc[ 6] = fmaf(xk, w1.z, acc[ 6]); acc[ 7] = fmaf(xk, w1.w, acc[ 7]);
            acc[ 8] = fmaf(xk, w2.x, acc[ 8]); acc[ 9] = fmaf(xk, w2.y, acc[ 9]);
            acc[10] = fmaf(xk, w2.z, acc[10]); acc[11] = fmaf(xk, w2.w, acc[11]);
            acc[12] = fmaf(xk, w3.x, acc[12]); acc[13] = fmaf(xk, w3.y, acc[13]);
            acc[14] = fmaf(xk, w3.z, acc[14]); acc[15] = fmaf(xk, w3.w, acc[15]);
            if (cg == 0) adacc = fmaf(xk, Wt[k * 68 + 64], adacc);
        }
    }

    float asp = 0.f;
    #pragma unroll
    for (int c = 0; c < 16; c++) asp = fmaf(acc[c], a_src[cg * 16 + c], asp);
    part[cg][lane] = asp;
    int n = n0 + lane;
    if (n < NODES) {
        float4* hrow = reinterpret_cast<float4*>(hs + (size_t)n * C1 + cg * 16);
        #pragma unroll
        for (int i = 0; i < 4; i++)
            hrow[i] = make_float4(acc[i * 4], acc[i * 4 + 1], acc[i * 4 + 2], acc[i * 4 + 3]);
    }
    __syncthreads();
    if (cg == 0 && n < NODES) {
        as_out[n] = part[0][lane] + part[1][lane] + part[2][lane] + part[3][lane];
        ad_out[n] = adacc;
    }
}

// ---------------- aggregation layer 1 ----------------
// wave per node; lane-parallel softmax (alpha = exp(e)/sum exp(e), max dropped
// algebraically; |e| <~ 12 << 88, clamp 60 as guard); 4x-unrolled row gathers.

__global__ __launch_bounds__(256) void k_agg1(const int* __restrict__ offs, const int* __restrict__ csr,
                                              const float* __restrict__ as1, const float* __restrict__ ad1,
                                              const float* __restrict__ hs1, const float* __restrict__ b1,
                                              float* __restrict__ h1) {
    int w = threadIdx.x >> 6, lane = threadIdx.x & 63;
    int node = blockIdx.x * 4 + w;
    if (node >= NODES) return;
    int e0 = offs[node], e1 = offs[node + 1];
    float adn = ad1[node];
    float acc0 = 0.f, acc1 = 0.f, acc2 = 0.f, acc3 = 0.f;
    float ssum = 0.f;
    for (int base = e0; base < e1; base += 64) {
        int cnt = e1 - base; if (cnt > 64) cnt = 64;
        bool valid = lane < cnt;
        int s = valid ? csr[base + lane] : 0;
        float v = valid ? (as1[s] + adn) : -INFINITY;
        v = v > 0.f ? v : NEG * v;
        float p = __expf(fminf(v, 60.f));
        ssum += p;
        int j = 0;
        for (; j + 4 <= cnt; j += 4) {
            int   s0 = __shfl(s, j),     s1 = __shfl(s, j + 1);
            int   s2 = __shfl(s, j + 2), s3 = __shfl(s, j + 3);
            float p0 = __shfl(p, j),     p1 = __shfl(p, j + 1);
            float p2 = __shfl(p, j + 2), p3 = __shfl(p, j + 3);
            acc0 = fmaf(p0, hs1[(size_t)s0 * C1 + lane], acc0);
            acc1 = fmaf(p1, hs1[(size_t)s1 * C1 + lane], acc1);
            acc2 = fmaf(p2, hs1[(size_t)s2 * C1 + lane], acc2);
            acc3 = fmaf(p3, hs1[(size_t)s3 * C1 + lane], acc3);
        }
        for (; j < cnt; j++) {
            int   sj = __shfl(s, j);
            float pj = __shfl(p, j);
            acc0 = fmaf(pj, hs1[(size_t)sj * C1 + lane], acc0);
        }
    }
    #pragma unroll
    for (int o = 32; o; o >>= 1) ssum += __shfl_xor(ssum, o);
    float acc = (acc0 + acc1) + (acc2 + acc3);
    h1[(size_t)node * C1 + lane] = acc / (ssum + 1e-16f) + b1[lane];
}

// ---------------- BN stats: deterministic per-block partials ----------------

__global__ __launch_bounds__(256) void k_bnstats(const float* __restrict__ h1, float* __restrict__ bnpart) {
    __shared__ float ls[256], lq[256];
    int t = threadIdx.x;
    int c = t & 63, g = t >> 6;
    float s = 0.f, q = 0.f;
    for (int n = blockIdx.x * 4 + g; n < NODES; n += BNBLK * 4) {
        float v = h1[(size_t)n * C1 + c];
        s += v;
        q = fmaf(v, v, q);
    }
    ls[t] = s; lq[t] = q;
    __syncthreads();
    if (t < 64) {
        bnpart[(size_t)blockIdx.x * 128 + t]      = ls[t] + ls[t + 64] + ls[t + 128] + ls[t + 192];
        bnpart[(size_t)blockIdx.x * 128 + 64 + t] = lq[t] + lq[t + 64] + lq[t + 128] + lq[t + 192];
    }
}

__global__ __launch_bounds__(64) void k_bnfinal(const float* __restrict__ bnpart,
                                                const float* __restrict__ gamma, const float* __restrict__ beta,
                                                float* bnscale, float* bnshift) {
    int c = threadIdx.x;
    if (c < C1) {
        float s = 0.f, q = 0.f;
        for (int b = 0; b < BNBLK; b++) {
            s += bnpart[(size_t)b * 128 + c];
            q += bnpart[(size_t)b * 128 + 64 + c];
        }
        float mu = s * (1.0f / NODES);
        float var = q * (1.0f / NODES) - mu * mu;
        if (var < 0.f) var = 0.f;
        float rinv = 1.0f / sqrtf(var + BNEPS);
        float sc = gamma[c] * rinv;
        bnscale[c] = sc;
        bnshift[c] = beta[c] - mu * sc;
    }
}

// ---------------- BN apply + ReLU + GEMM2 (+alpha dots) ----------------

__global__ __launch_bounds__(256) void k_bngemm2(const float* __restrict__ h1, const float* __restrict__ bnscale,
                                                 const float* __restrict__ bnshift, const float* __restrict__ W2s,
                                                 const float* __restrict__ wad2, const float* __restrict__ a2s,
                                                 float* __restrict__ hs2, float* __restrict__ as2,
                                                 float* __restrict__ ad2) {
    int n = blockIdx.x * 256 + threadIdx.x;
    if (n >= NODES) return;
    const float4* hr = reinterpret_cast<const float4*>(h1 + (size_t)n * C1);
    float h0 = 0.f, h1v = 0.f, adv = 0.f;
    #pragma unroll
    for (int c4 = 0; c4 < 16; c4++) {
        float4 v = hr[c4];
        float vv[4] = {v.x, v.y, v.z, v.w};
        #pragma unroll
        for (int j = 0; j < 4; j++) {
            int c = c4 * 4 + j;
            float y = fmaf(vv[j], bnscale[c], bnshift[c]);
            y = fmaxf(y, 0.f);
            h0 = fmaf(y, W2s[c * 2 + 0], h0);
            h1v = fmaf(y, W2s[c * 2 + 1], h1v);
            adv = fmaf(y, wad2[c], adv);
        }
    }
    hs2[n * 2 + 0] = h0;
    hs2[n * 2 + 1] = h1v;
    as2[n] = fmaf(h0, a2s[0], h1v * a2s[1]);
    ad2[n] = adv;
}

// ---------------- aggregation layer 2: wave per node, fully lane-parallel ----------------

__global__ __launch_bounds__(256) void k_agg2(const int* __restrict__ offs, const int* __restrict__ csr,
                                              const float* __restrict__ as2, const float* __restrict__ ad2,
                                              const float* __restrict__ hs2, const float* __restrict__ b2,
                                              float* __restrict__ out) {
    int w = threadIdx.x >> 6, lane = threadIdx.x & 63;
    int node = blockIdx.x * 4 + w;
    if (node >= NODES) return;
    int e0 = offs[node], e1 = offs[node + 1];
    float adn = ad2[node];
    float ssum = 0.f, A0 = 0.f, A1 = 0.f;
    const float2* h2 = reinterpret_cast<const float2*>(hs2);
    for (int base = e0; base < e1; base += 64) {
        int e = base + lane;
        bool valid = e < e1;
        int s = valid ? csr[e] : 0;
        float v = valid ? (as2[s] + adn) : -INFINITY;
        v = v > 0.f ? v : NEG * v;
        float p = __expf(fminf(v, 60.f));
        ssum += p;
        float2 hv = valid ? h2[s] : make_float2(0.f, 0.f);
        A0 = fmaf(p, hv.x, A0);
        A1 = fmaf(p, hv.y, A1);
    }
    #pragma unroll
    for (int o = 32; o; o >>= 1) {
        ssum += __shfl_xor(ssum, o);
        A0   += __shfl_xor(A0, o);
        A1   += __shfl_xor(A1, o);
    }
    if (lane == 0) {
        float inv = 1.0f / (ssum + 1e-16f);
        float2 r = make_float2(fmaf(A0, inv, b2[0]), fmaf(A1, inv, b2[1]));
        reinterpret_cast<float2*>(out)[node] = r;
    }
}

// ---------------- host ----------------

static inline size_t align256(size_t x) { return (x + 255) & ~size_t(255); }

extern "C" void kernel_launch(void* const* d_in, const int* in_sizes, int n_in,
                              void* d_out, int out_size, void* d_ws, size_t ws_size,
                              hipStream_t stream) {
    const float* x     = (const float*)d_in[0];
    const int*   ei    = (const int*)d_in[1];
    const float* W1s   = (const float*)d_in[2];
    const float* W1d   = (const float*)d_in[3];
    const float* a1s   = (const float*)d_in[4];
    const float* a1d   = (const float*)d_in[5];
    const float* b1    = (const float*)d_in[6];
    const float* gamma = (const float*)d_in[7];
    const float* beta  = (const float*)d_in[8];
    const float* W2s   = (const float*)d_in[9];
    const float* W2d   = (const float*)d_in[10];
    const float* a2s   = (const float*)d_in[11];
    const float* a2d   = (const float*)d_in[12];
    const float* b2    = (const float*)d_in[13];
    float* out = (float*)d_out;

    char* w = (char*)d_ws;
    size_t off = 0;
    auto alloc = [&](size_t bytes) -> void* {
        void* p = w + off;
        off = align256(off + bytes);
        return p;
    };
    int* offs     = (int*)alloc((size_t)(NODES + 1) * 4);
    int* bcur     = (int*)alloc(256 * 4);
    int* bbase    = (int*)alloc(256 * 4);
    int* csr      = (int*)alloc((size_t)ETOT * 4);
    float* hs1    = (float*)alloc((size_t)NODES * C1 * 4);
    float* as1    = (float*)alloc((size_t)NODES * 4);
    float* ad1    = (float*)alloc((size_t)NODES * 4);
    float* h1     = (float*)alloc((size_t)NODES * C1 * 4);   // also aliases csr_tmp (see below)
    float* hs2    = (float*)alloc((size_t)NODES * 2 * 4);
    float* as2    = (float*)alloc((size_t)NODES * 4);
    float* ad2    = (float*)alloc((size_t)NODES * 4);
    float* wad1   = (float*)alloc(FIN * 4);
    float* wad2   = (float*)alloc(C1 * 4);
    float* bnpart = (float*)alloc((size_t)BNBLK * 128 * 4);
    float* bnsc   = (float*)alloc(64 * 4);
    float* bnsh   = (float*)alloc(64 * 4);
    if (off > ws_size) return;

    // csr_tmp (NBUCK*PCAP ints = 9.7MB) aliases h1 (25.6MB): k_build fully consumes
    // csr_tmp before k_agg1 produces h1 (in-order stream => safe).
    unsigned* csr_tmp = (unsigned*)h1;

    k_zero256<<<1, 256, 0, stream>>>(bcur);
    k_part<<<(NEDGE + PTILE - 1) / PTILE, 256, 0, stream>>>(ei, bcur, csr_tmp);
    k_bscan<<<1, 256, 0, stream>>>(bcur, bbase);
    k_build<<<NBUCK, 256, 0, stream>>>(csr_tmp, bcur, bbase, offs, csr);
    k_prep<<<1, 128, 0, stream>>>(W1d, a1d, W2d, a2d, wad1, wad2);
    k_gemm1<<<(NODES + 63) / 64, 256, 0, stream>>>(x, W1s, wad1, a1s, hs1, as1, ad1);
    k_agg1<<<(NODES + 3) / 4, 256, 0, stream>>>(offs, csr, as1, ad1, hs1, b1, h1);
    k_bnstats<<<BNBLK, 256, 0, stream>>>(h1, bnpart);
    k_bnfinal<<<1, 64, 0, stream>>>(bnpart, gamma, beta, bnsc, bnsh);
    k_bngemm2<<<(NODES + 255) / 256, 256, 0, stream>>>(h1, bnsc, bnsh, W2s, wad2, a2s, hs2, as2, ad2);
    k_agg2<<<(NODES + 3) / 4, 256, 0, stream>>>(offs, csr, as2, ad2, hs2, b2, out);
}